// Round 10
// baseline (148.480 us; speedup 1.0000x reference)
//
#include <hip/hip_runtime.h>
#include <cfloat>
#include <stdint.h>

#define B_   16
#define N_   2048
#define KK   10          // window = K+1
#define H_   128
#define SUB  32          // chunk size
#define NCH  (N_ / SUB)  // 64 chunks

#define RANK_BLOCKS (B_ * 32)                  // 512: 64-elem segments, 256 thr
#define WEFF_OUT    (H_ * KK * 2 + H_)         // 2688 outputs
#define WEFF_BLOCKS ((WEFF_OUT * 4) / 256)     // 42 (4 lanes/output, exact)

__device__ inline uint32_t f32_ordered(float f) {
    uint32_t u = __float_as_uint(f);
    return (u & 0x80000000u) ? ~u : (u | 0x80000000u);
}

// ---- setup (unchanged, ~6us): rank-by-count sort; unique keys ->
// exact permutation, output bitwise-identical to the original bitonic.
__global__ __launch_bounds__(256) void setup_kernel(
    const float* __restrict__ x,
    const float* __restrict__ Wconv, const float* __restrict__ bconv,
    const float* __restrict__ b1,    const float* __restrict__ W2,
    const float* __restrict__ b2,
    float4* __restrict__ xsorted,    // [B][N] (px,py,sm,orig_idx_bits)
    float*  __restrict__ weff,       // [H*20]
    float*  __restrict__ btot)       // [H]
{
#pragma clang fp contract(off)
    __shared__ __align__(16) uint64_t sk[N_];   // 16 KB
    __shared__ int pcnt[4 * 64];
    const int tid = threadIdx.x;

    if (blockIdx.x >= RANK_BLOCKS) {
        const int g = (blockIdx.x - RANK_BLOCKS) * 256 + tid;
        const int o = g >> 2, q = g & 3;
        float acc = 0.f;
        if (o < H_ * KK * 2) {
            const int e = o / 20, r = o % 20, k = r >> 1, c = r & 1;
            const float* w2p = W2 + e * H_ + q * 32;
            const float* wcp = Wconv + (q * 32) * (2 * KK) + c * KK + k;
#pragma unroll 8
            for (int h = 0; h < 32; ++h)
                acc += w2p[h] * wcp[h * (2 * KK)];
        } else {
            const int e = o - H_ * KK * 2;
            const float* w2p = W2 + e * H_ + q * 32;
            const float* bcp = bconv + q * 32;
#pragma unroll 8
            for (int h = 0; h < 32; ++h) acc += w2p[h] * bcp[h];
        }
        acc += __shfl_xor(acc, 1, 64);
        acc += __shfl_xor(acc, 2, 64);
        if (q == 0) {
            if (o < H_ * KK * 2) weff[o] = acc;
            else {
                const int e = o - H_ * KK * 2;
                btot[e] = acc + b1[e] + b2[e];
            }
        }
        return;
    }

    const int b  = blockIdx.x >> 5;
    const int sg = blockIdx.x & 31;
    const float2* xb = (const float2*)(x + (size_t)b * N_ * 2);

    for (int i = tid; i < N_; i += 256)
        sk[i] = ((uint64_t)f32_ordered(xb[i].x) << 32) | (uint32_t)i;
    __syncthreads();

    const int el = tid & 63;
    const int pt = tid >> 6;
    const uint64_t kown = sk[sg * 64 + el];
    const ulonglong2* sk2 = (const ulonglong2*)sk + pt * 256;
    int cnt = 0;
#pragma unroll 2
    for (int j = 0; j < 256; j += 4) {
        ulonglong2 t0 = sk2[j + 0];
        ulonglong2 t1 = sk2[j + 1];
        ulonglong2 t2 = sk2[j + 2];
        ulonglong2 t3 = sk2[j + 3];
        cnt += (int)(t0.x < kown) + (int)(t0.y < kown)
             + (int)(t1.x < kown) + (int)(t1.y < kown)
             + (int)(t2.x < kown) + (int)(t2.y < kown)
             + (int)(t3.x < kown) + (int)(t3.y < kown);
    }
    pcnt[pt * 64 + el] = cnt;
    __syncthreads();

    if (tid < 64) {
        const int r = pcnt[tid] + pcnt[64 + tid] + pcnt[128 + tid] + pcnt[192 + tid];
        const int i = sg * 64 + tid;
        float2 p = xb[i];
        float sm = p.x * p.x + p.y * p.y;   // no FMA (np sum convention)
        xsorted[(size_t)b * N_ + r] =
            make_float4(p.x, p.y, sm, __uint_as_float((uint32_t)i));
    }
}

// ---- main kernel v9: v8's algorithm, re-parameterized for FULL OCCUPANCY.
// v8 post-mortem: LDS 38.4KB allows 4 blocks/CU but grid 512 = only 2/CU
// -> 27% occupancy, stall-bound (VALUBusy 42%). v9: 32 queries per block
// (one chunk), Q=4 queries/wave x S=16 sub-lanes (2 positions/chunk/lane),
// grid = 1024 = exactly 4 blocks/CU -> 32 waves/CU structural. Sub-lane
// lists hold 6 real + 4 sentinels (bit-22-tagged, unique per lane, d2 field
// = FLT_MAX, > every real key) -> merge protocols and both bound proofs
// (exact post-phase-1 union-10th; max_group(hk[1]) refresh) carry over.
// Same candidate unions, keys, and gate validity -> identical selected
// top-10 -> output bitwise identical to v8.
__global__ __launch_bounds__(512, 8) void knn_conv_kernel(
    const float4* __restrict__ xsorted,
    const float* __restrict__ W1,
    const float* __restrict__ weff,
    const float* __restrict__ btot,
    float* __restrict__ out)
{
#pragma clang fp contract(off)
    __shared__ float4 xs4[N_];           // 32 KB
    __shared__ float  wcoord[32 * 21];   //  2.6 KB

    const int tid  = threadIdx.x;
    const int w    = tid >> 6;        // wave 0..7
    const int l    = tid & 63;
    const int r    = tid & 15;        // sub-lane: candidate slice (16)
    const int qm   = tid >> 4;        // query within block (0..31)
    const int b    = blockIdx.x >> 6;
    const int tile = blockIdx.x & 63; // tile == chunk index

    const float4* xb = xsorted + (size_t)b * N_;
    for (int i = tid; i < N_; i += 512) xs4[i] = xb[i];
    __syncthreads();

    const float4 qv = xs4[tile * 32 + qm];
    const float  qx = qv.x, qy = qv.y, sqn = qv.z;
    const int    gfirst = tile * 32 + w * 4;      // wave's 4-query group
    const float  qa  = xs4[gfirst].x;             // group x-range (uniform)
    const float  qbx = xs4[gfirst + 3].x;

    // sorted-10 of u64 keys: (d2_bits<<32)|(orig_idx<<11)|sorted_pos.
    // Sentinel: d2 field FLT_MAX, bit 22 set (no real key has it: real low32
    // < 2^22), unique per lane -> ordering and one-winner protocol safe.
    const uint64_t KSENT = (((uint64_t)0x7F7FFFFFu) << 32) | 0x400000u | (uint32_t)l;
    uint64_t hk[KK];
#pragma unroll
    for (int j = 0; j < KK; ++j) hk[j] = KSENT;
    float h9d  = FLT_MAX;   // 10th-best of own candidate subset
    float shb  = FLT_MAX;   // per-query shared bound (monotone nonincreasing)
    float gate = FLT_MAX;   // fminf(h9d, shb)

    auto insert = [&](float dc, float cw, int m) {
        uint32_t oi = __float_as_uint(cw);
        uint64_t key = ((uint64_t)__float_as_uint(dc) << 32)
                     | (oi << 11) | (uint32_t)m;
        if (key < hk[KK - 1]) {
#pragma unroll
            for (int j = KK - 1; j >= 1; --j) {
                bool cj  = key < hk[j];
                bool cjm = key < hk[j - 1];
                hk[j] = cj ? (cjm ? hk[j - 1] : key) : hk[j];
            }
            hk[0] = (key < hk[0]) ? key : hk[0];
        }
        h9d  = __uint_as_float((uint32_t)(hk[KK - 1] >> 32));
        gate = fminf(h9d, shb);
    };

    // sub-lane r scans positions mc+r, mc+r+16 (per-lane addresses; 16
    // distinct float4 lines x 4-way broadcast = conflict-free).
    auto scan_chunk = [&](int mc) {
        const int m0 = mc + r;
        float4 c0 = xs4[m0 + 0];
        float4 c1 = xs4[m0 + 16];
        float dc0, dc1;
        { float s = sqn + c0.z; float pr = qx * c0.x;
          float dt = __builtin_fmaf(qy, c0.y, pr);
          float d2 = __builtin_fmaf(-2.0f, dt, s); dc0 = d2 > 0.0f ? d2 : 0.0f; }
        { float s = sqn + c1.z; float pr = qx * c1.x;
          float dt = __builtin_fmaf(qy, c1.y, pr);
          float d2 = __builtin_fmaf(-2.0f, dt, s); dc1 = d2 > 0.0f ? d2 : 0.0f; }
        if (dc0 <= gate) insert(dc0, c0.w, m0 + 0);
        if (dc1 <= gate) insert(dc1, c1.w, m0 + 16);
    };

    // bounds refresh: per-query bound = min(min_group(h9d), max_group(hk1)),
    // folded monotonically into shb; returns wave-max over the 4 queries.
    // hk[1] validity: each sub-lane's 2 smallest reals <= its hk[1] once it
    // holds >=2 reals (phase 1 gives 6), so >=32 union elems <= max -> the
    // union 10th <= max.
    auto bounds = [&]() {
        float gb = h9d;
        gb = fminf(gb, __shfl_xor(gb, 1, 64));
        gb = fminf(gb, __shfl_xor(gb, 2, 64));
        gb = fminf(gb, __shfl_xor(gb, 4, 64));
        gb = fminf(gb, __shfl_xor(gb, 8, 64));
        float h1 = __uint_as_float((uint32_t)(hk[1] >> 32));
        h1 = fmaxf(h1, __shfl_xor(h1, 1, 64));
        h1 = fmaxf(h1, __shfl_xor(h1, 2, 64));
        h1 = fmaxf(h1, __shfl_xor(h1, 4, 64));
        h1 = fmaxf(h1, __shfl_xor(h1, 8, 64));
        shb  = fminf(shb, fminf(gb, h1));
        gate = fminf(h9d, shb);
        float wm = shb;
        wm = fmaxf(wm, __shfl_xor(wm, 16, 64));
        wm = fmaxf(wm, __shfl_xor(wm, 32, 64));
        return wm;   // max over the wave's 4 queries of their bounds
    };

    // phase 1: home chunk trio (6 real candidates/lane; 96/query union).
    int c0s = tile - 1;
    if (c0s < 0) c0s = 0;
    if (c0s > NCH - 3) c0s = NCH - 3;
    scan_chunk((c0s + 0) * SUB);
    scan_chunk((c0s + 1) * SUB);
    scan_chunk((c0s + 2) * SUB);

    // EXACT current 10th-best of the 96-candidate union (non-destructive
    // 16-list merge over register copies). Every union-top-10 element is in
    // its own sub-lane's top-10 (6 reals < 10 slots -> all retained), so 10
    // selections find exactly the union's 10 smallest; sentinels (> all
    // reals) can never win. The 10th's d2 is a valid tight gate.
    {
        uint64_t tc[KK];
#pragma unroll
        for (int j = 0; j < KK; ++j) tc[j] = hk[j];
        uint64_t last = 0;
#pragma unroll
        for (int sel = 0; sel < KK; ++sel) {
            uint64_t v  = tc[0];
            uint64_t t1 = __shfl_xor((unsigned long long)v, 1, 64);
            uint64_t m1 = v  < t1 ? v  : t1;
            uint64_t t2 = __shfl_xor((unsigned long long)m1, 2, 64);
            uint64_t m2 = m1 < t2 ? m1 : t2;
            uint64_t t4 = __shfl_xor((unsigned long long)m2, 4, 64);
            uint64_t m4 = m2 < t4 ? m2 : t4;
            uint64_t t8 = __shfl_xor((unsigned long long)m4, 8, 64);
            uint64_t vm = m4 < t8 ? m4 : t8;
            if (v == vm) {
#pragma unroll
                for (int j = 0; j < KK - 1; ++j) tc[j] = tc[j + 1];
                tc[KK - 1] = 0xFFFFFFFFFFFFFFFFull;
            }
            last = vm;
        }
        shb  = __uint_as_float((uint32_t)(last >> 32));
        gate = fminf(h9d, shb);
    }

    // phase 2: two-pointer outward, step 1, both sides per bounds() refresh
    // (stale-wm on the right is conservative: bounds only shrink). Gaps are
    // monotone per side -> a failed skip test kills that side for good.
    int  cl = c0s - 1, cr = c0s + 3;
    bool la = (cl >= 0), ra = (cr <= NCH - 1);
    while (la || ra) {
        float wm = bounds();
        if (la) {
            float gl = qa - xs4[cl * SUB + SUB - 1].x;            // >= 0
            if (__builtin_fmaf(gl, gl, -4e-6f) > wm) la = false;  // margin >> f32 d2 err
            else { scan_chunk(cl * SUB); cl -= 1; la = (cl >= 0); }
        }
        if (ra) {
            float gr = xs4[cr * SUB].x - qbx;                     // >= 0
            if (__builtin_fmaf(gr, gr, -4e-6f) > wm) ra = false;
            else { scan_chunk(cr * SUB); cr += 1; ra = (cr <= NCH - 1); }
        }
    }

    // hoist epilogue weights (latency overlaps merge + barrier)
    const int e = tid & 127;
    float we[20];
    {
        const float4* wp = (const float4*)(weff + e * 20);
#pragma unroll
        for (int rr = 0; rr < 5; ++rr) {
            float4 v = wp[rr];
            we[4 * rr + 0] = v.x; we[4 * rr + 1] = v.y;
            we[4 * rr + 2] = v.z; we[4 * rr + 3] = v.w;
        }
    }
    const float w1x = W1[e * 2 + 0];
    const float w1y = W1[e * 2 + 1];
    const float bt  = btot[e];

    // register merge: 16 sub-lane lists per query live in lanes (qm, r) --
    // head = hk[0]; winner shift-registers. Keys unique -> exactly one
    // winner per selection; 96 reals >= 10 -> sentinels never selected.
    {
#pragma unroll
        for (int sel = 0; sel < KK; ++sel) {
            uint64_t v  = hk[0];
            uint64_t t1 = __shfl_xor((unsigned long long)v, 1, 64);
            uint64_t m1 = v  < t1 ? v  : t1;
            uint64_t t2 = __shfl_xor((unsigned long long)m1, 2, 64);
            uint64_t m2 = m1 < t2 ? m1 : t2;
            uint64_t t4 = __shfl_xor((unsigned long long)m2, 4, 64);
            uint64_t m4 = m2 < t4 ? m2 : t4;
            uint64_t t8 = __shfl_xor((unsigned long long)m4, 8, 64);
            uint64_t vm = m4 < t8 ? m4 : t8;
            if (v == vm) {
#pragma unroll
                for (int j = 0; j < KK - 1; ++j) hk[j] = hk[j + 1];
                hk[KK - 1] = 0xFFFFFFFFFFFFFFFFull;
            }
            if (r == 0) {
                float4 c = xs4[(int)(vm & 0x7FF)];
                const int k = (KK - 1) - sel;          // flip: nearest -> k=9
                wcoord[qm * 21 + 2 * k + 0] = c.x;
                wcoord[qm * 21 + 2 * k + 1] = c.y;
            }
        }
    }
    __syncthreads();

    // epilogue: thread -> channel e; 32 queries x 128 channels; rows
    // scattered to ORIGINAL indices (coalesced per wave-store).
    const int qb_ = tid >> 7;                  // 0..3
    const size_t obase = (size_t)b * N_ * H_;
#pragma unroll
    for (int jj = 0; jj < 8; ++jj) {
        const int qq = qb_ + 4 * jj;
        float4 xq = xs4[tile * 32 + qq];
        uint32_t orig = __float_as_uint(xq.w);
        const float* wc = &wcoord[qq * 21];
        float acc = bt;
        acc += xq.x * w1x;
        acc += xq.y * w1y;
#pragma unroll
        for (int k = 0; k < KK; ++k) {
            acc += wc[2 * k + 0] * we[2 * k + 0];
            acc += wc[2 * k + 1] * we[2 * k + 1];
        }
        out[obase + (size_t)orig * H_ + e] = acc;
    }
}

extern "C" void kernel_launch(void* const* d_in, const int* in_sizes, int n_in,
                              void* d_out, int out_size, void* d_ws, size_t ws_size,
                              hipStream_t stream) {
    const float* x     = (const float*)d_in[0];
    const float* Wconv = (const float*)d_in[1];
    const float* bconv = (const float*)d_in[2];
    const float* W1    = (const float*)d_in[3];
    const float* b1    = (const float*)d_in[4];
    const float* W2    = (const float*)d_in[5];
    const float* b2    = (const float*)d_in[6];
    float* out  = (float*)d_out;
    float* weff = (float*)d_ws;                           // 2560 floats
    float* btot = weff + H_ * KK * 2;                     // 128 floats
    float4* xsorted = (float4*)((char*)d_ws + 16384);     // 16*2048*16B

    setup_kernel<<<dim3(RANK_BLOCKS + WEFF_BLOCKS), dim3(256), 0, stream>>>(
        x, Wconv, bconv, b1, W2, b2, xsorted, weff, btot);
    knn_conv_kernel<<<dim3(B_ * NCH), dim3(512), 0, stream>>>(
        xsorted, W1, weff, btot, out);
}

// Round 11
// 143.310 us; speedup vs baseline: 1.0361x; 1.0361x over previous
//
#include <hip/hip_runtime.h>
#include <cfloat>
#include <stdint.h>

#define B_   16
#define N_   2048
#define KK   10          // window = K+1
#define H_   128
#define SUB  32          // chunk size
#define NCH  (N_ / SUB)  // 64 chunks

#define RANK_BLOCKS (B_ * 32)                  // 512: 64-elem segments, 256 thr
#define WEFF_OUT    (H_ * KK * 2 + H_)         // 2688 outputs
#define WEFF_BLOCKS ((WEFF_OUT * 4) / 256)     // 42 (4 lanes/output, exact)

__device__ inline uint32_t f32_ordered(float f) {
    uint32_t u = __float_as_uint(f);
    return (u & 0x80000000u) ? ~u : (u | 0x80000000u);
}

// ---- setup (unchanged, ~6us): rank-by-count sort; unique keys ->
// exact permutation, output bitwise-identical to the original bitonic.
__global__ __launch_bounds__(256) void setup_kernel(
    const float* __restrict__ x,
    const float* __restrict__ Wconv, const float* __restrict__ bconv,
    const float* __restrict__ b1,    const float* __restrict__ W2,
    const float* __restrict__ b2,
    float4* __restrict__ xsorted,    // [B][N] (px,py,sm,orig_idx_bits)
    float*  __restrict__ weff,       // [H*20]
    float*  __restrict__ btot)       // [H]
{
#pragma clang fp contract(off)
    __shared__ __align__(16) uint64_t sk[N_];   // 16 KB
    __shared__ int pcnt[4 * 64];
    const int tid = threadIdx.x;

    if (blockIdx.x >= RANK_BLOCKS) {
        const int g = (blockIdx.x - RANK_BLOCKS) * 256 + tid;
        const int o = g >> 2, q = g & 3;
        float acc = 0.f;
        if (o < H_ * KK * 2) {
            const int e = o / 20, r = o % 20, k = r >> 1, c = r & 1;
            const float* w2p = W2 + e * H_ + q * 32;
            const float* wcp = Wconv + (q * 32) * (2 * KK) + c * KK + k;
#pragma unroll 8
            for (int h = 0; h < 32; ++h)
                acc += w2p[h] * wcp[h * (2 * KK)];
        } else {
            const int e = o - H_ * KK * 2;
            const float* w2p = W2 + e * H_ + q * 32;
            const float* bcp = bconv + q * 32;
#pragma unroll 8
            for (int h = 0; h < 32; ++h) acc += w2p[h] * bcp[h];
        }
        acc += __shfl_xor(acc, 1, 64);
        acc += __shfl_xor(acc, 2, 64);
        if (q == 0) {
            if (o < H_ * KK * 2) weff[o] = acc;
            else {
                const int e = o - H_ * KK * 2;
                btot[e] = acc + b1[e] + b2[e];
            }
        }
        return;
    }

    const int b  = blockIdx.x >> 5;
    const int sg = blockIdx.x & 31;
    const float2* xb = (const float2*)(x + (size_t)b * N_ * 2);

    for (int i = tid; i < N_; i += 256)
        sk[i] = ((uint64_t)f32_ordered(xb[i].x) << 32) | (uint32_t)i;
    __syncthreads();

    const int el = tid & 63;
    const int pt = tid >> 6;
    const uint64_t kown = sk[sg * 64 + el];
    const ulonglong2* sk2 = (const ulonglong2*)sk + pt * 256;
    int cnt = 0;
#pragma unroll 2
    for (int j = 0; j < 256; j += 4) {
        ulonglong2 t0 = sk2[j + 0];
        ulonglong2 t1 = sk2[j + 1];
        ulonglong2 t2 = sk2[j + 2];
        ulonglong2 t3 = sk2[j + 3];
        cnt += (int)(t0.x < kown) + (int)(t0.y < kown)
             + (int)(t1.x < kown) + (int)(t1.y < kown)
             + (int)(t2.x < kown) + (int)(t2.y < kown)
             + (int)(t3.x < kown) + (int)(t3.y < kown);
    }
    pcnt[pt * 64 + el] = cnt;
    __syncthreads();

    if (tid < 64) {
        const int r = pcnt[tid] + pcnt[64 + tid] + pcnt[128 + tid] + pcnt[192 + tid];
        const int i = sg * 64 + tid;
        float2 p = xb[i];
        float sm = p.x * p.x + p.y * p.y;   // no FMA (np sum convention)
        xsorted[(size_t)b * N_ + r] =
            make_float4(p.x, p.y, sm, __uint_as_float((uint32_t)i));
    }
}

// ---- main kernel v10: v8's geometry (8 queries/wave x 8 sub-lanes; best
// measured) with the SERIAL CHAINS cut:
//  (1) phase-1: 12 ladder-inserts (12 x ~80cy dependent select chains)
//      replaced by 12 batched loads + odd-even transposition sort-12
//      network (branchless, ILP-6/round, ~100cy depth). First 10 of the
//      sorted-12 == top-10 by key == v8's ladder result exactly.
//  (2) merge #1 (exact union-10th bound) now ALSO writes wcoord (it finds
//      winners in ascending order already).
//  (3) if NO lane of the wave inserted during phase 2 (wave-uniform ballot),
//      the final merge is SKIPPED -- wcoord from merge #1 is already final.
// Phase 2, bounds refresh, epilogue: byte-identical to v8. Output bitwise
// identical to v8/R3.
__global__ __launch_bounds__(512, 4) void knn_conv_kernel(
    const float4* __restrict__ xsorted,
    const float* __restrict__ W1,
    const float* __restrict__ weff,
    const float* __restrict__ btot,
    float* __restrict__ out)
{
#pragma clang fp contract(off)
    __shared__ float4 xs4[N_];           // 32 KB
    __shared__ float  wcoord[64 * 21];   //  5.25 KB

    const int tid  = threadIdx.x;
    const int w    = tid >> 6;        // wave 0..7
    const int r    = tid & 7;         // sub-lane: candidate slice
    const int qm   = tid >> 3;        // query within tile (0..63)
    const int b    = blockIdx.x >> 5;
    const int tile = blockIdx.x & 31;

    const float4* xb = xsorted + (size_t)b * N_;
    for (int i = tid; i < N_; i += 512) xs4[i] = xb[i];
    __syncthreads();

    const float4 qv = xs4[tile * 64 + qm];
    const float  qx = qv.x, qy = qv.y, sqn = qv.z;
    const int    gfirst = tile * 64 + w * 8;      // wave's query group
    const float  qa  = xs4[gfirst].x;             // group x-range (uniform)
    const float  qbx = xs4[gfirst + 7].x;

    // sorted-10 of u64 keys: (d2_bits<<32)|(orig_idx<<11)|sorted_pos.
    uint64_t hk[KK];
    float h9d  = FLT_MAX;   // 10th-best of own candidate subset
    float shb  = FLT_MAX;   // per-query shared bound (monotone nonincreasing)
    float gate = FLT_MAX;   // fminf(h9d, shb)
    bool  p2ins = false;    // any phase-2 insert by this lane

    auto insert = [&](float dc, float cw, int m) {
        uint32_t oi = __float_as_uint(cw);
        uint64_t key = ((uint64_t)__float_as_uint(dc) << 32)
                     | (oi << 11) | (uint32_t)m;
        if (key < hk[KK - 1]) {
#pragma unroll
            for (int j = KK - 1; j >= 1; --j) {
                bool cj  = key < hk[j];
                bool cjm = key < hk[j - 1];
                hk[j] = cj ? (cjm ? hk[j - 1] : key) : hk[j];
            }
            hk[0] = (key < hk[0]) ? key : hk[0];
            p2ins = true;
        }
        h9d  = __uint_as_float((uint32_t)(hk[KK - 1] >> 32));
        gate = fminf(h9d, shb);
    };

    // sub-lane r scans positions mc+r, +8, +16, +24 (per-lane addresses;
    // 8 distinct float4 lines x 8-way broadcast = conflict-free).
    auto scan_chunk = [&](int mc) {
        const int m0 = mc + r;
        float4 c0 = xs4[m0 + 0];
        float4 c1 = xs4[m0 + 8];
        float4 c2 = xs4[m0 + 16];
        float4 c3 = xs4[m0 + 24];
        float dc0, dc1, dc2, dc3;
        { float s = sqn + c0.z; float pr = qx * c0.x;
          float dt = __builtin_fmaf(qy, c0.y, pr);
          float d2 = __builtin_fmaf(-2.0f, dt, s); dc0 = d2 > 0.0f ? d2 : 0.0f; }
        { float s = sqn + c1.z; float pr = qx * c1.x;
          float dt = __builtin_fmaf(qy, c1.y, pr);
          float d2 = __builtin_fmaf(-2.0f, dt, s); dc1 = d2 > 0.0f ? d2 : 0.0f; }
        { float s = sqn + c2.z; float pr = qx * c2.x;
          float dt = __builtin_fmaf(qy, c2.y, pr);
          float d2 = __builtin_fmaf(-2.0f, dt, s); dc2 = d2 > 0.0f ? d2 : 0.0f; }
        { float s = sqn + c3.z; float pr = qx * c3.x;
          float dt = __builtin_fmaf(qy, c3.y, pr);
          float d2 = __builtin_fmaf(-2.0f, dt, s); dc3 = d2 > 0.0f ? d2 : 0.0f; }
        if (dc0 <= gate) insert(dc0, c0.w, m0 + 0);
        if (dc1 <= gate) insert(dc1, c1.w, m0 + 8);
        if (dc2 <= gate) insert(dc2, c2.w, m0 + 16);
        if (dc3 <= gate) insert(dc3, c3.w, m0 + 24);
    };

    // bounds refresh (v8): per-query bound = min(min_group(h9d),
    // max_group(hk1)) folded monotonically into shb; returns wave-max.
    auto bounds = [&]() {
        float gb = h9d;
        gb = fminf(gb, __shfl_xor(gb, 1, 64));
        gb = fminf(gb, __shfl_xor(gb, 2, 64));
        gb = fminf(gb, __shfl_xor(gb, 4, 64));
        float h1 = __uint_as_float((uint32_t)(hk[1] >> 32));
        h1 = fmaxf(h1, __shfl_xor(h1, 1, 64));
        h1 = fmaxf(h1, __shfl_xor(h1, 2, 64));
        h1 = fmaxf(h1, __shfl_xor(h1, 4, 64));
        shb  = fminf(shb, fminf(gb, h1));
        gate = fminf(h9d, shb);
        float wm = shb;
        wm = fmaxf(wm, __shfl_xor(wm, 8,  64));
        wm = fmaxf(wm, __shfl_xor(wm, 16, 64));
        wm = fmaxf(wm, __shfl_xor(wm, 32, 64));
        return wm;   // max over the wave's 8 queries of their bounds
    };

    // phase 1: home chunk trio -> 12 batched loads, 12 keys, sort-12
    // network (odd-even transposition, 12 rounds), hk = first 10.
    const int home = tile * 2 + (w >> 2);
    int c0s = home - 1;
    if (c0s < 0) c0s = 0;
    if (c0s > NCH - 3) c0s = NCH - 3;
    {
        const int m0 = c0s * SUB + r;
        uint64_t k12[12];
#pragma unroll
        for (int ch = 0; ch < 3; ++ch) {
            const int mb = m0 + ch * SUB;
            float4 c0 = xs4[mb + 0];
            float4 c1 = xs4[mb + 8];
            float4 c2 = xs4[mb + 16];
            float4 c3 = xs4[mb + 24];
            float dc0, dc1, dc2, dc3;
            { float s = sqn + c0.z; float pr = qx * c0.x;
              float dt = __builtin_fmaf(qy, c0.y, pr);
              float d2 = __builtin_fmaf(-2.0f, dt, s); dc0 = d2 > 0.0f ? d2 : 0.0f; }
            { float s = sqn + c1.z; float pr = qx * c1.x;
              float dt = __builtin_fmaf(qy, c1.y, pr);
              float d2 = __builtin_fmaf(-2.0f, dt, s); dc1 = d2 > 0.0f ? d2 : 0.0f; }
            { float s = sqn + c2.z; float pr = qx * c2.x;
              float dt = __builtin_fmaf(qy, c2.y, pr);
              float d2 = __builtin_fmaf(-2.0f, dt, s); dc2 = d2 > 0.0f ? d2 : 0.0f; }
            { float s = sqn + c3.z; float pr = qx * c3.x;
              float dt = __builtin_fmaf(qy, c3.y, pr);
              float d2 = __builtin_fmaf(-2.0f, dt, s); dc3 = d2 > 0.0f ? d2 : 0.0f; }
            k12[ch * 4 + 0] = ((uint64_t)__float_as_uint(dc0) << 32)
                            | (__float_as_uint(c0.w) << 11) | (uint32_t)(mb + 0);
            k12[ch * 4 + 1] = ((uint64_t)__float_as_uint(dc1) << 32)
                            | (__float_as_uint(c1.w) << 11) | (uint32_t)(mb + 8);
            k12[ch * 4 + 2] = ((uint64_t)__float_as_uint(dc2) << 32)
                            | (__float_as_uint(c2.w) << 11) | (uint32_t)(mb + 16);
            k12[ch * 4 + 3] = ((uint64_t)__float_as_uint(dc3) << 32)
                            | (__float_as_uint(c3.w) << 11) | (uint32_t)(mb + 24);
        }
        // odd-even transposition sort, 12 rounds (branchless, ILP-6)
#pragma unroll
        for (int rnd = 0; rnd < 12; ++rnd) {
            if ((rnd & 1) == 0) {
#pragma unroll
                for (int i = 0; i < 12; i += 2) {
                    uint64_t a = k12[i], bk = k12[i + 1];
                    bool lt = a < bk;
                    k12[i]     = lt ? a  : bk;
                    k12[i + 1] = lt ? bk : a;
                }
            } else {
#pragma unroll
                for (int i = 1; i < 11; i += 2) {
                    uint64_t a = k12[i], bk = k12[i + 1];
                    bool lt = a < bk;
                    k12[i]     = lt ? a  : bk;
                    k12[i + 1] = lt ? bk : a;
                }
            }
        }
#pragma unroll
        for (int j = 0; j < KK; ++j) hk[j] = k12[j];
        h9d  = __uint_as_float((uint32_t)(hk[KK - 1] >> 32));
        gate = h9d;
    }

    // merge #1: EXACT current 10th-best of the 96-candidate union
    // (non-destructive 8-list merge) + wcoord writes (winners arrive in
    // ascending order, same protocol as the final merge).
    {
        uint64_t tc[KK];
#pragma unroll
        for (int j = 0; j < KK; ++j) tc[j] = hk[j];
        uint64_t last = 0;
#pragma unroll
        for (int sel = 0; sel < KK; ++sel) {
            uint64_t v  = tc[0];
            uint64_t t1 = __shfl_xor((unsigned long long)v, 1, 64);
            uint64_t m1 = v  < t1 ? v  : t1;
            uint64_t t2 = __shfl_xor((unsigned long long)m1, 2, 64);
            uint64_t m2 = m1 < t2 ? m1 : t2;
            uint64_t t4 = __shfl_xor((unsigned long long)m2, 4, 64);
            uint64_t vm = m2 < t4 ? m2 : t4;
            if (v == vm) {
#pragma unroll
                for (int j = 0; j < KK - 1; ++j) tc[j] = tc[j + 1];
                tc[KK - 1] = 0xFFFFFFFFFFFFFFFFull;
            }
            if (r == 0) {
                float4 c = xs4[(int)(vm & 0x7FF)];
                const int k = (KK - 1) - sel;          // flip: nearest -> k=9
                wcoord[qm * 21 + 2 * k + 0] = c.x;
                wcoord[qm * 21 + 2 * k + 1] = c.y;
            }
            last = vm;
        }
        shb  = __uint_as_float((uint32_t)(last >> 32));
        gate = fminf(h9d, shb);
    }

    // phase 2 (v8): two-pointer outward, step 1, both sides per bounds()
    // refresh. Gaps monotone per side -> failed skip kills the side.
    int  cl = c0s - 1, cr = c0s + 3;
    bool la = (cl >= 0), ra = (cr <= NCH - 1);
    while (la || ra) {
        float wm = bounds();
        if (la) {
            float gl = qa - xs4[cl * SUB + SUB - 1].x;            // >= 0
            if (__builtin_fmaf(gl, gl, -4e-6f) > wm) la = false;  // margin >> f32 d2 err
            else { scan_chunk(cl * SUB); cl -= 1; la = (cl >= 0); }
        }
        if (ra) {
            float gr = xs4[cr * SUB].x - qbx;                     // >= 0
            if (__builtin_fmaf(gr, gr, -4e-6f) > wm) ra = false;
            else { scan_chunk(cr * SUB); cr += 1; ra = (cr <= NCH - 1); }
        }
    }

    // hoist epilogue weights (latency overlaps merge + barrier)
    const int e = tid & 127;
    float we[20];
    {
        const float4* wp = (const float4*)(weff + e * 20);
#pragma unroll
        for (int rr = 0; rr < 5; ++rr) {
            float4 v = wp[rr];
            we[4 * rr + 0] = v.x; we[4 * rr + 1] = v.y;
            we[4 * rr + 2] = v.z; we[4 * rr + 3] = v.w;
        }
    }
    const float w1x = W1[e * 2 + 0];
    const float w1y = W1[e * 2 + 1];
    const float bt  = btot[e];

    // final merge, ONLY if some lane of this wave inserted in phase 2
    // (wave-uniform ballot). Otherwise wcoord from merge #1 is already
    // the exact final top-10 (no list changed since).
    if (__ballot(p2ins)) {
#pragma unroll
        for (int sel = 0; sel < KK; ++sel) {
            uint64_t v  = hk[0];
            uint64_t t1 = __shfl_xor((unsigned long long)v, 1, 64);
            uint64_t m1 = v  < t1 ? v  : t1;
            uint64_t t2 = __shfl_xor((unsigned long long)m1, 2, 64);
            uint64_t m2 = m1 < t2 ? m1 : t2;
            uint64_t t4 = __shfl_xor((unsigned long long)m2, 4, 64);
            uint64_t vm = m2 < t4 ? m2 : t4;
            if (v == vm) {
#pragma unroll
                for (int j = 0; j < KK - 1; ++j) hk[j] = hk[j + 1];
                hk[KK - 1] = 0xFFFFFFFFFFFFFFFFull;
            }
            if (r == 0) {
                float4 c = xs4[(int)(vm & 0x7FF)];
                const int k = (KK - 1) - sel;          // flip: nearest -> k=9
                wcoord[qm * 21 + 2 * k + 0] = c.x;
                wcoord[qm * 21 + 2 * k + 1] = c.y;
            }
        }
    }
    __syncthreads();

    // epilogue: thread -> channel e; rows scattered to ORIGINAL indices
    // (128 consecutive floats per row, coalesced per wave-store).
    const int qb_ = tid >> 7;
    const size_t obase = (size_t)b * N_ * H_;
#pragma unroll
    for (int jj = 0; jj < 16; ++jj) {
        const int qq = qb_ + 4 * jj;
        float4 xq = xs4[tile * 64 + qq];
        uint32_t orig = __float_as_uint(xq.w);
        const float* wc = &wcoord[qq * 21];
        float acc = bt;
        acc += xq.x * w1x;
        acc += xq.y * w1y;
#pragma unroll
        for (int k = 0; k < KK; ++k) {
            acc += wc[2 * k + 0] * we[2 * k + 0];
            acc += wc[2 * k + 1] * we[2 * k + 1];
        }
        out[obase + (size_t)orig * H_ + e] = acc;
    }
}

extern "C" void kernel_launch(void* const* d_in, const int* in_sizes, int n_in,
                              void* d_out, int out_size, void* d_ws, size_t ws_size,
                              hipStream_t stream) {
    const float* x     = (const float*)d_in[0];
    const float* Wconv = (const float*)d_in[1];
    const float* bconv = (const float*)d_in[2];
    const float* W1    = (const float*)d_in[3];
    const float* b1    = (const float*)d_in[4];
    const float* W2    = (const float*)d_in[5];
    const float* b2    = (const float*)d_in[6];
    float* out  = (float*)d_out;
    float* weff = (float*)d_ws;                           // 2560 floats
    float* btot = weff + H_ * KK * 2;                     // 128 floats
    float4* xsorted = (float4*)((char*)d_ws + 16384);     // 16*2048*16B

    setup_kernel<<<dim3(RANK_BLOCKS + WEFF_BLOCKS), dim3(256), 0, stream>>>(
        x, Wconv, bconv, b1, W2, b2, xsorted, weff, btot);
    knn_conv_kernel<<<dim3(B_ * (N_ / 64)), dim3(512), 0, stream>>>(
        xsorted, W1, weff, btot, out);
}